// Round 7
// baseline (81.138 us; speedup 1.0000x reference)
//
#include <hip/hip_runtime.h>
#include <hip/hip_bf16.h>

// bottom (8,256,128,128) f32; w1 (256,1,3,3); a1,w2,b2 (256,)
// out: res (8,256,64,64) ++ pexp (8,256,64,64), f32.  K=3 S=2 P=1 -> 64x64.
// R7: no data staging. One 256-thread block per plane (2048 blocks, 8/CU,
// 32 waves/CU). Phase 1: streaming abs-max from global (discard). Phase 2:
// window compute reading global again -> L1/L2-hot. Row-carry in registers.

#define HW 16384       // 128*128
#define N_OUT 8388608  // 8*256*64*64

__device__ __forceinline__ float hw_log2(float x) { return __builtin_amdgcn_logf(x); }
__device__ __forceinline__ float hw_exp2(float x) { return __builtin_amdgcn_exp2f(x); }
__device__ __forceinline__ float hw_rcp(float x)  { return __builtin_amdgcn_rcpf(x); }

struct Row { float xm, x0, x1; };   // window cols 2wo-1, 2wo, 2wo+1

__device__ __forceinline__ Row load_row(const float* plane, int hi, int lane) {
    float2 v = *reinterpret_cast<const float2*>(plane + hi * 128 + lane * 2);
    float xm = __shfl_up(v.y, 1, 64);
    if (lane == 0) xm = 0.f;        // zero pad col -1
    Row r; r.xm = xm; r.x0 = v.x; r.x1 = v.y; return r;
}

__global__ __launch_bounds__(256, 8) void fused_ppool_l2(
    const float* __restrict__ bottom,
    const float* __restrict__ w1,   // (256,3,3)
    const float* __restrict__ a1,
    const float* __restrict__ w2,
    const float* __restrict__ b2,
    float* __restrict__ out) {
    __shared__ float smax[4];

    const int t    = threadIdx.x;
    const int wid  = t >> 6;        // 0..3
    const int lane = t & 63;
    const int bc   = blockIdx.x;    // one plane per block
    const int c    = bc & 255;

    const float* plane = bottom + (size_t)bc * HW;

    // ---- Phase 1: streaming abs-max (values discarded; lands in L1/L2) ----
    const float4* p4 = reinterpret_cast<const float4*>(plane);
    float m0 = 0.f, m1 = 0.f;
    #pragma unroll
    for (int k = 0; k < 16; k += 2) {
        float4 a = p4[t + k * 256];
        float4 b = p4[t + (k + 1) * 256];
        m0 = fmaxf(m0, fmaxf(fmaxf(fabsf(a.x), fabsf(a.y)),
                             fmaxf(fabsf(a.z), fabsf(a.w))));
        m1 = fmaxf(m1, fmaxf(fmaxf(fabsf(b.x), fabsf(b.y)),
                             fmaxf(fabsf(b.z), fabsf(b.w))));
    }
    float mx = fmaxf(m0, m1);
    #pragma unroll
    for (int off = 32; off; off >>= 1)
        mx = fmaxf(mx, __shfl_down(mx, off, 64));
    if (lane == 0) smax[wid] = mx;
    __syncthreads();
    const float m = fmaxf(fmaxf(smax[0], smax[1]), fmaxf(smax[2], smax[3]));
    const float inv_m = hw_rcp(m + 1.0f);

    // Block-uniform channel params.
    float wk[9];
    #pragma unroll
    for (int k = 0; k < 9; ++k) wk[k] = w1[c * 9 + k];
    const float slope = a1[c];
    const float ww2   = w2[c];
    const float bb2   = b2[c];

    float* outres = out + (size_t)bc * 4096;
    float* outp   = out + N_OUT + (size_t)bc * 4096;

    // ---- Phase 2: wave wid computes output rows wid*16 .. wid*16+15 ----
    const int ho0 = wid * 16;
    Row top;                         // row 2*ho-1, carried across iterations
    {
        const int hi = 2 * ho0 - 1;  // -1 only for wid==0
        if (hi >= 0) top = load_row(plane, hi, lane);
        else { top.xm = 0.f; top.x0 = 0.f; top.x1 = 0.f; }
    }

    #pragma unroll
    for (int rr = 0; rr < 16; ++rr) {
        const int ho = ho0 + rr;
        Row mid = load_row(plane, 2 * ho,     lane);   // rows 0..126
        Row bot = load_row(plane, 2 * ho + 1, lane);   // rows 1..127

        // depthwise 3x3 conv of (x * inv_m)
        float v = wk[0] * top.xm + wk[1] * top.x0 + wk[2] * top.x1
                + wk[3] * mid.xm + wk[4] * mid.x0 + wk[5] * mid.x1
                + wk[6] * bot.xm + wk[7] * bot.x0 + wk[8] * bot.x1;
        v *= inv_m;
        v = v > 0.f ? v : slope * v;            // PReLU
        float p = v * ww2 + bb2;                // 1x1 dw conv + bias
        p = fminf(fmaxf(p, 1.0f), 110.0f);      // hardtanh

        // power-mean: x^p = exp2(p*log2(x)); x=0 -> exp2(-inf) = 0.
        float s = 0.f;
        s += hw_exp2(p * hw_log2(fmaxf(top.xm, 0.f)));
        s += hw_exp2(p * hw_log2(fmaxf(top.x0, 0.f)));
        s += hw_exp2(p * hw_log2(fmaxf(top.x1, 0.f)));
        s += hw_exp2(p * hw_log2(fmaxf(mid.xm, 0.f)));
        s += hw_exp2(p * hw_log2(fmaxf(mid.x0, 0.f)));
        s += hw_exp2(p * hw_log2(fmaxf(mid.x1, 0.f)));
        s += hw_exp2(p * hw_log2(fmaxf(bot.xm, 0.f)));
        s += hw_exp2(p * hw_log2(fmaxf(bot.x0, 0.f)));
        s += hw_exp2(p * hw_log2(fmaxf(bot.x1, 0.f)));

        float mp  = s * (1.0f / 9.0f) + 1e-12f;
        float res = hw_exp2(hw_log2(mp) * hw_rcp(p));

        outres[ho * 64 + lane] = res;
        outp  [ho * 64 + lane] = p;

        top = bot;                  // row 2ho+1 == row 2(ho+1)-1
    }
}

extern "C" void kernel_launch(void* const* d_in, const int* in_sizes, int n_in,
                              void* d_out, int out_size, void* d_ws, size_t ws_size,
                              hipStream_t stream) {
    const float* bottom = (const float*)d_in[0];
    const float* w1     = (const float*)d_in[1];
    const float* a1     = (const float*)d_in[2];
    const float* w2     = (const float*)d_in[3];
    const float* b2     = (const float*)d_in[4];
    float* out = (float*)d_out;

    fused_ppool_l2<<<2048, 256, 0, stream>>>(bottom, w1, a1, w2, b2, out);
}

// Round 8
// 56.044 us; speedup vs baseline: 1.4477x; 1.4477x over previous
//
#include <hip/hip_runtime.h>
#include <hip/hip_bf16.h>

// bottom (8,256,128,128) f32; w1 (256,1,3,3); a1,w2,b2 (256,)
// out: res (8,256,64,64) ++ pexp (8,256,64,64), f32.  K=3 S=2 P=1 -> 64x64.
// R8: two-kernel split. A: per-plane abs-max (pure stream, full BW).
// B: fused conv+pow compute, no LDS/barriers, row-carry in regs; input
// reads served by L3 (134MB < 256MB, just streamed by A). log2 computed
// once per loaded element (16 trans/output instead of 21).

#define HW 16384       // 128*128
#define N_OUT 8388608  // 8*256*64*64

__device__ __forceinline__ float hw_log2(float x) { return __builtin_amdgcn_logf(x); }
__device__ __forceinline__ float hw_exp2(float x) { return __builtin_amdgcn_exp2f(x); }
__device__ __forceinline__ float hw_rcp(float x)  { return __builtin_amdgcn_rcpf(x); }

// ---------- Kernel A: per-(b,c) max(|x|)+1 ----------
__global__ __launch_bounds__(256, 8) void plane_max_kernel(
    const float* __restrict__ bottom, float* __restrict__ m_out) {
    const int bc = blockIdx.x;
    const int t  = threadIdx.x;
    const float4* p4 = reinterpret_cast<const float4*>(bottom + (size_t)bc * HW);
    float m0 = 0.f, m1 = 0.f;
    #pragma unroll
    for (int k = 0; k < 16; k += 2) {
        float4 a = p4[t + k * 256];
        float4 b = p4[t + (k + 1) * 256];
        m0 = fmaxf(m0, fmaxf(fmaxf(fabsf(a.x), fabsf(a.y)),
                             fmaxf(fabsf(a.z), fabsf(a.w))));
        m1 = fmaxf(m1, fmaxf(fmaxf(fabsf(b.x), fabsf(b.y)),
                             fmaxf(fabsf(b.z), fabsf(b.w))));
    }
    float mx = fmaxf(m0, m1);
    #pragma unroll
    for (int off = 32; off; off >>= 1)
        mx = fmaxf(mx, __shfl_down(mx, off, 64));
    __shared__ float smax[4];
    if ((t & 63) == 0) smax[t >> 6] = mx;
    __syncthreads();
    if (t == 0)
        m_out[bc] = fmaxf(fmaxf(smax[0], smax[1]), fmaxf(smax[2], smax[3])) + 1.0f;
}

// ---------- Kernel B: fused exponent-branch + p-pooling ----------
struct RowC { float xm, x0, x1, lm, l0, l1; };  // raw x and log2(relu(x))

__device__ __forceinline__ RowC load_rowc(const float* plane, int hi, int lane) {
    RowC r;
    float2 v = *reinterpret_cast<const float2*>(plane + hi * 128 + lane * 2);
    r.x0 = v.x; r.x1 = v.y;
    r.l0 = hw_log2(fmaxf(v.x, 0.f));            // log2(0) = -inf -> exp2 = 0
    r.l1 = hw_log2(fmaxf(v.y, 0.f));
    r.xm = __shfl_up(v.y, 1, 64);
    r.lm = __shfl_up(r.l1, 1, 64);
    if (lane == 0) { r.xm = 0.f; r.lm = -__builtin_inff(); }  // zero pad col -1
    return r;
}

__global__ __launch_bounds__(256) void ppool_compute(
    const float* __restrict__ bottom,
    const float* __restrict__ w1,   // (256,3,3)
    const float* __restrict__ a1,
    const float* __restrict__ w2,
    const float* __restrict__ b2,
    const float* __restrict__ m_in, // (2048,)
    float* __restrict__ out) {
    const int t    = threadIdx.x;
    const int wid  = t >> 6;        // 0..3
    const int lane = t & 63;
    const int bc   = blockIdx.x;
    const int c    = bc & 255;

    const float* plane = bottom + (size_t)bc * HW;
    const float inv_m = hw_rcp(m_in[bc]);

    float wk[9];
    #pragma unroll
    for (int k = 0; k < 9; ++k) wk[k] = w1[c * 9 + k];
    const float slope = a1[c];
    const float ww2   = w2[c];
    const float bb2   = b2[c];

    float* outres = out + (size_t)bc * 4096;
    float* outp   = out + N_OUT + (size_t)bc * 4096;

    // Wave wid: output rows ho0..ho0+15 with input-row carry (33 row loads).
    const int ho0 = wid * 16;
    RowC top;
    if (wid == 0) {                 // row -1: zero pad
        top.xm = top.x0 = top.x1 = 0.f;
        top.lm = top.l0 = top.l1 = -__builtin_inff();
    } else {
        top = load_rowc(plane, 2 * ho0 - 1, lane);
    }

    #pragma unroll
    for (int rr = 0; rr < 16; ++rr) {
        const int ho = ho0 + rr;
        RowC mid = load_rowc(plane, 2 * ho,     lane);   // rows 0..126
        RowC bot = load_rowc(plane, 2 * ho + 1, lane);   // rows 1..127

        // depthwise 3x3 conv of (x * inv_m)
        float v = wk[0] * top.xm + wk[1] * top.x0 + wk[2] * top.x1
                + wk[3] * mid.xm + wk[4] * mid.x0 + wk[5] * mid.x1
                + wk[6] * bot.xm + wk[7] * bot.x0 + wk[8] * bot.x1;
        v *= inv_m;
        v = v > 0.f ? v : slope * v;            // PReLU
        float p = v * ww2 + bb2;                // 1x1 dw conv + bias
        p = fminf(fmaxf(p, 1.0f), 110.0f);      // hardtanh

        // power-mean: relu(x)^p = exp2(p * lx), lx precomputed at load
        float s = hw_exp2(p * top.lm) + hw_exp2(p * top.l0) + hw_exp2(p * top.l1)
                + hw_exp2(p * mid.lm) + hw_exp2(p * mid.l0) + hw_exp2(p * mid.l1)
                + hw_exp2(p * bot.lm) + hw_exp2(p * bot.l0) + hw_exp2(p * bot.l1);

        float mp  = s * (1.0f / 9.0f) + 1e-12f;
        float res = hw_exp2(hw_log2(mp) * hw_rcp(p));

        outres[ho * 64 + lane] = res;
        outp  [ho * 64 + lane] = p;

        top = bot;                  // row 2ho+1 == row 2(ho+1)-1
    }
}

extern "C" void kernel_launch(void* const* d_in, const int* in_sizes, int n_in,
                              void* d_out, int out_size, void* d_ws, size_t ws_size,
                              hipStream_t stream) {
    const float* bottom = (const float*)d_in[0];
    const float* w1     = (const float*)d_in[1];
    const float* a1     = (const float*)d_in[2];
    const float* w2     = (const float*)d_in[3];
    const float* b2     = (const float*)d_in[4];
    float* out = (float*)d_out;
    float* m   = (float*)d_ws;      // 2048 floats

    plane_max_kernel<<<2048, 256, 0, stream>>>(bottom, m);
    ppool_compute  <<<2048, 256, 0, stream>>>(bottom, w1, a1, w2, b2, m, out);
}

// Round 9
// 39.783 us; speedup vs baseline: 2.0395x; 1.4087x over previous
//
#include <hip/hip_runtime.h>
#include <hip/hip_bf16.h>

// bottom (8,256,128,128) f32; w1 (256,1,3,3); a1,w2,b2 (256,)
// out: res (8,256,64,64) ++ pexp (8,256,64,64), f32.  K=3 S=2 P=1 -> 64x64.
// R9 = R3 structure (one 1024-thr block per plane, 64KiB LDS, 2 blocks/CU)
// + compute diet: per-element log2 (16 trans/output vs 21), row-carry
// (2.25 LDS row reads/output), incremental conv accumulation (low VGPR).

#define HW 16384       // 128*128
#define N_OUT 8388608  // 8*256*64*64
#define NEG_INF (-__builtin_inff())

__device__ __forceinline__ float hw_log2(float x) { return __builtin_amdgcn_logf(x); }
__device__ __forceinline__ float hw_exp2(float x) { return __builtin_amdgcn_exp2f(x); }
__device__ __forceinline__ float hw_rcp(float x)  { return __builtin_amdgcn_rcpf(x); }

__global__ __launch_bounds__(1024, 8) void fused_ppool_v9(
    const float* __restrict__ bottom,
    const float* __restrict__ w1,   // (256,3,3)
    const float* __restrict__ a1,
    const float* __restrict__ w2,
    const float* __restrict__ b2,
    float* __restrict__ out) {
    __shared__ float plane[HW];     // 64 KiB
    __shared__ float smax[16];

    const int t    = threadIdx.x;
    const int wid  = t >> 6;        // 0..15
    const int lane = t & 63;
    const int bc   = blockIdx.x;    // one plane per block
    const int c    = bc & 255;

    // ---- Phase 1: global -> LDS, abs-max from registers (2-acc ILP) ----
    const float4* src = reinterpret_cast<const float4*>(bottom + (size_t)bc * HW);
    float4* pl4 = reinterpret_cast<float4*>(plane);
    float m0 = 0.f, m1 = 0.f;
    #pragma unroll
    for (int k = 0; k < 4; k += 2) {
        float4 a = src[t + k * 1024];
        float4 b = src[t + (k + 1) * 1024];
        pl4[t + k * 1024] = a;
        pl4[t + (k + 1) * 1024] = b;
        m0 = fmaxf(m0, fmaxf(fmaxf(fabsf(a.x), fabsf(a.y)),
                             fmaxf(fabsf(a.z), fabsf(a.w))));
        m1 = fmaxf(m1, fmaxf(fmaxf(fabsf(b.x), fabsf(b.y)),
                             fmaxf(fabsf(b.z), fabsf(b.w))));
    }
    float mx = fmaxf(m0, m1);
    #pragma unroll
    for (int off = 32; off; off >>= 1)
        mx = fmaxf(mx, __shfl_down(mx, off, 64));
    if (lane == 0) smax[wid] = mx;
    __syncthreads();

    float mm = 0.f;
    #pragma unroll
    for (int k = 0; k < 16; k += 4)
        mm = fmaxf(mm, fmaxf(fmaxf(smax[k], smax[k + 1]),
                             fmaxf(smax[k + 2], smax[k + 3])));
    const float inv_m = hw_rcp(mm + 1.0f);

    // Block-uniform channel params (scalar loads).
    const float wk0 = w1[c * 9 + 0], wk1 = w1[c * 9 + 1], wk2 = w1[c * 9 + 2];
    const float wk3 = w1[c * 9 + 3], wk4 = w1[c * 9 + 4], wk5 = w1[c * 9 + 5];
    const float wk6 = w1[c * 9 + 6], wk7 = w1[c * 9 + 7], wk8 = w1[c * 9 + 8];
    const float slope = a1[c];
    const float ww2   = w2[c];
    const float bb2   = b2[c];

    float* outres = out + (size_t)bc * 4096;
    float* outp   = out + N_OUT + (size_t)bc * 4096;

    // ---- Phase 2: wave wid -> output rows ho0..ho0+3, row-carry ----
    const int ho0 = wid * 4;
    float lt0, lt1;     // log2(relu(x)) of carried row 2ho-1, cols 2wo,2wo+1
    float A_cur;        // conv partial for current ho (top-row contribution)
    {
        const int hi = 2 * ho0 - 1;     // -1 only for wid==0
        if (hi >= 0) {
            float2 v = *reinterpret_cast<const float2*>(&plane[hi * 128 + lane * 2]);
            float xm = __shfl_up(v.y, 1, 64); if (lane == 0) xm = 0.f;
            A_cur = wk0 * xm + wk1 * v.x + wk2 * v.y;
            lt0 = hw_log2(fmaxf(v.x, 0.f));
            lt1 = hw_log2(fmaxf(v.y, 0.f));
        } else {
            A_cur = 0.f; lt0 = NEG_INF; lt1 = NEG_INF;
        }
    }

    #pragma unroll
    for (int rr = 0; rr < 4; ++rr) {
        const int ho = ho0 + rr;
        float lm0, lm1, lb0, lb1, A_next;
        {   // mid row 2ho (0..126): conv contribution + logs
            float2 v = *reinterpret_cast<const float2*>(&plane[(2 * ho) * 128 + lane * 2]);
            float xm = __shfl_up(v.y, 1, 64); if (lane == 0) xm = 0.f;
            A_cur += wk3 * xm + wk4 * v.x + wk5 * v.y;
            lm0 = hw_log2(fmaxf(v.x, 0.f));
            lm1 = hw_log2(fmaxf(v.y, 0.f));
        }
        {   // bot row 2ho+1 (1..127): closes A_cur, opens A_next
            float2 v = *reinterpret_cast<const float2*>(&plane[(2 * ho + 1) * 128 + lane * 2]);
            float xm = __shfl_up(v.y, 1, 64); if (lane == 0) xm = 0.f;
            A_cur += wk6 * xm + wk7 * v.x + wk8 * v.y;
            A_next = wk0 * xm + wk1 * v.x + wk2 * v.y;
            lb0 = hw_log2(fmaxf(v.x, 0.f));
            lb1 = hw_log2(fmaxf(v.y, 0.f));
        }

        float v = A_cur * inv_m;                // conv(x/m)
        v = v > 0.f ? v : slope * v;            // PReLU
        float p = v * ww2 + bb2;                // 1x1 dw conv + bias
        p = fminf(fmaxf(p, 1.0f), 110.0f);      // hardtanh (v_med3)

        // left-neighbor logs via shuffle (recomputed, not carried: saves regs)
        float ltm = __shfl_up(lt1, 1, 64); if (lane == 0) ltm = NEG_INF;
        float lmm = __shfl_up(lm1, 1, 64); if (lane == 0) lmm = NEG_INF;
        float lbm = __shfl_up(lb1, 1, 64); if (lane == 0) lbm = NEG_INF;

        // relu(x)^p = exp2(p * log2(relu(x))); log2(0)=-inf -> 0
        float s = hw_exp2(p * ltm) + hw_exp2(p * lt0) + hw_exp2(p * lt1)
                + hw_exp2(p * lmm) + hw_exp2(p * lm0) + hw_exp2(p * lm1)
                + hw_exp2(p * lbm) + hw_exp2(p * lb0) + hw_exp2(p * lb1);

        float mp  = s * (1.0f / 9.0f) + 1e-12f;
        float res = hw_exp2(hw_log2(mp) * hw_rcp(p));

        outres[ho * 64 + lane] = res;
        outp  [ho * 64 + lane] = p;

        lt0 = lb0; lt1 = lb1; A_cur = A_next;   // carry row 2ho+1 == 2(ho+1)-1
    }
}

extern "C" void kernel_launch(void* const* d_in, const int* in_sizes, int n_in,
                              void* d_out, int out_size, void* d_ws, size_t ws_size,
                              hipStream_t stream) {
    const float* bottom = (const float*)d_in[0];
    const float* w1     = (const float*)d_in[1];
    const float* a1     = (const float*)d_in[2];
    const float* w2     = (const float*)d_in[3];
    const float* b2     = (const float*)d_in[4];
    float* out = (float*)d_out;

    fused_ppool_v9<<<2048, 1024, 0, stream>>>(bottom, w1, a1, w2, b2, out);
}

// Round 10
// 36.450 us; speedup vs baseline: 2.2260x; 1.0914x over previous
//
#include <hip/hip_runtime.h>
#include <hip/hip_bf16.h>

// bottom (8,256,128,128) f32; w1 (256,1,3,3); a1,w2,b2 (256,)
// out: res (8,256,64,64) ++ pexp (8,256,64,64), f32.  K=3 S=2 P=1 -> 64x64.
// R10: no plane staging at all. One 1024-thr block per plane (2 blocks/CU,
// 32 waves/CU, LDS = 64 B). Each thread loads its 9 window rows (float2)
// straight from global; abs-max, log2(relu(x)), and conv partials are all
// computed DURING the load phase (m-independent). One barrier for the max;
// post-barrier only the p-dependent exp2 tail. No LDS round-trip.

#define HW 16384       // 128*128
#define N_OUT 8388608  // 8*256*64*64
#define NEG_INF (-__builtin_inff())

__device__ __forceinline__ float hw_log2(float x) { return __builtin_amdgcn_logf(x); }
__device__ __forceinline__ float hw_exp2(float x) { return __builtin_amdgcn_exp2f(x); }
__device__ __forceinline__ float hw_rcp(float x)  { return __builtin_amdgcn_rcpf(x); }

__global__ __launch_bounds__(1024, 8) void fused_ppool_v10(
    const float* __restrict__ bottom,
    const float* __restrict__ w1,   // (256,3,3)
    const float* __restrict__ a1,
    const float* __restrict__ w2,
    const float* __restrict__ b2,
    float* __restrict__ out) {
    __shared__ float smax[16];

    const int t    = threadIdx.x;
    const int wid  = t >> 6;        // 0..15
    const int lane = t & 63;
    const int bc   = blockIdx.x;    // one plane per block
    const int c    = bc & 255;

    const float* plane = bottom + (size_t)bc * HW;

    float wk[9];
    #pragma unroll
    for (int k = 0; k < 9; ++k) wk[k] = w1[c * 9 + k];   // block-uniform
    const float slope = a1[c];
    const float ww2   = w2[c];
    const float bb2   = b2[c];

    // Wave wid owns output rows ho0..ho0+3 -> input rows 2*ho0-1 .. 2*ho0+7.
    const int ho0   = wid * 4;
    const int hbase = 2 * ho0 - 1;  // -1 only for wid==0, r==0

    float lx0[9], lx1[9];           // log2(relu(x)) at cols 2wo, 2wo+1
    float A[4];                     // conv accumulators for 4 output rows
    A[0] = A[1] = A[2] = A[3] = 0.f;
    float mx = 0.f;

    // ---- Load phase: 9 row loads; max/logs/conv computed as data arrives ----
    #pragma unroll
    for (int r = 0; r < 9; ++r) {
        const int hi = hbase + r;   // wave-uniform
        float a = 0.f, b = 0.f;
        if (hi >= 0) {
            float2 v = *reinterpret_cast<const float2*>(plane + hi * 128 + lane * 2);
            a = v.x; b = v.y;
        }
        mx = fmaxf(mx, fmaxf(fabsf(a), fabsf(b)));
        float xm = __shfl_up(b, 1, 64);
        if (lane == 0) xm = 0.f;    // zero pad col -1
        // row r (= window row k of output rr when r == 2*rr + k)
        #pragma unroll
        for (int rr = 0; rr < 4; ++rr) {
            const int k = r - 2 * rr;
            if (k >= 0 && k <= 2)
                A[rr] += wk[3 * k] * xm + wk[3 * k + 1] * a + wk[3 * k + 2] * b;
        }
        lx0[r] = hw_log2(fmaxf(a, 0.f));    // log2(0) = -inf -> exp2 = 0
        lx1[r] = hw_log2(fmaxf(b, 0.f));
    }

    // ---- Plane max reduce (the only cross-wave dependency) ----
    #pragma unroll
    for (int off = 32; off; off >>= 1)
        mx = fmaxf(mx, __shfl_down(mx, off, 64));
    if (lane == 0) smax[wid] = mx;
    __syncthreads();
    float mm = smax[0];
    #pragma unroll
    for (int k = 1; k < 16; ++k) mm = fmaxf(mm, smax[k]);
    const float inv_m = hw_rcp(mm + 1.0f);

    // Left-neighbor logs (col 2wo-1) via shuffle of col 2wo+1.
    float lxm[9];
    #pragma unroll
    for (int r = 0; r < 9; ++r) {
        float s = __shfl_up(lx1[r], 1, 64);
        lxm[r] = (lane == 0) ? NEG_INF : s;
    }

    float* outres = out + (size_t)bc * 4096;
    float* outp   = out + N_OUT + (size_t)bc * 4096;

    // ---- p-dependent tail: 9 exp2 + finals per output ----
    #pragma unroll
    for (int rr = 0; rr < 4; ++rr) {
        float v = A[rr] * inv_m;                // conv(x/m)
        v = v > 0.f ? v : slope * v;            // PReLU
        float p = v * ww2 + bb2;                // 1x1 dw conv + bias
        p = fminf(fmaxf(p, 1.0f), 110.0f);      // hardtanh

        float s = 0.f;
        #pragma unroll
        for (int k = 0; k < 3; ++k) {
            const int r = 2 * rr + k;
            s += hw_exp2(p * lxm[r]) + hw_exp2(p * lx0[r]) + hw_exp2(p * lx1[r]);
        }
        float mp  = s * (1.0f / 9.0f) + 1e-12f;
        float res = hw_exp2(hw_log2(mp) * hw_rcp(p));

        const int ho = ho0 + rr;
        outres[ho * 64 + lane] = res;
        outp  [ho * 64 + lane] = p;
    }
}

extern "C" void kernel_launch(void* const* d_in, const int* in_sizes, int n_in,
                              void* d_out, int out_size, void* d_ws, size_t ws_size,
                              hipStream_t stream) {
    const float* bottom = (const float*)d_in[0];
    const float* w1     = (const float*)d_in[1];
    const float* a1     = (const float*)d_in[2];
    const float* w2     = (const float*)d_in[3];
    const float* b2     = (const float*)d_in[4];
    float* out = (float*)d_out;

    fused_ppool_v10<<<2048, 1024, 0, stream>>>(bottom, w1, a1, w2, b2, out);
}

// Round 11
// 35.721 us; speedup vs baseline: 2.2714x; 1.0204x over previous
//
#include <hip/hip_runtime.h>
#include <hip/hip_bf16.h>

// bottom (8,256,128,128) f32; w1 (256,1,3,3); a1,w2,b2 (256,)
// out: res (8,256,64,64) ++ pexp (8,256,64,64), f32.  K=3 S=2 P=1 -> 64x64.
// R11 = R10 (direct-global loads, one barrier, p-tail) +
//   (1) lxm shuffles hoisted pre-barrier (overlap sibling block's mem phase)
//   (2) non-temporal output stores (write-once data bypasses caches)
//   (3) 2-acc exp2 sum (trans-pipe ILP).

#define HW 16384       // 128*128
#define N_OUT 8388608  // 8*256*64*64
#define NEG_INF (-__builtin_inff())

__device__ __forceinline__ float hw_log2(float x) { return __builtin_amdgcn_logf(x); }
__device__ __forceinline__ float hw_exp2(float x) { return __builtin_amdgcn_exp2f(x); }
__device__ __forceinline__ float hw_rcp(float x)  { return __builtin_amdgcn_rcpf(x); }

__global__ __launch_bounds__(1024, 8) void fused_ppool_v11(
    const float* __restrict__ bottom,
    const float* __restrict__ w1,   // (256,3,3)
    const float* __restrict__ a1,
    const float* __restrict__ w2,
    const float* __restrict__ b2,
    float* __restrict__ out) {
    __shared__ float smax[16];

    const int t    = threadIdx.x;
    const int wid  = t >> 6;        // 0..15
    const int lane = t & 63;
    const int bc   = blockIdx.x;    // one plane per block
    const int c    = bc & 255;

    const float* plane = bottom + (size_t)bc * HW;

    float wk[9];
    #pragma unroll
    for (int k = 0; k < 9; ++k) wk[k] = w1[c * 9 + k];   // block-uniform
    const float slope = a1[c];
    const float ww2   = w2[c];
    const float bb2   = b2[c];

    // Wave wid owns output rows ho0..ho0+3 -> input rows 2*ho0-1 .. 2*ho0+7.
    const int ho0   = wid * 4;
    const int hbase = 2 * ho0 - 1;  // -1 only for wid==0, r==0

    float lx0[9], lx1[9], lxm[9];   // log2(relu(x)) at cols 2wo, 2wo+1, 2wo-1
    float A[4];                     // conv accumulators for 4 output rows
    A[0] = A[1] = A[2] = A[3] = 0.f;
    float mx = 0.f;

    // ---- Load phase: 9 row loads; max/logs/conv/shuffles as data arrives ----
    #pragma unroll
    for (int r = 0; r < 9; ++r) {
        const int hi = hbase + r;   // wave-uniform
        float a = 0.f, b = 0.f;
        if (hi >= 0) {
            float2 v = *reinterpret_cast<const float2*>(plane + hi * 128 + lane * 2);
            a = v.x; b = v.y;
        }
        mx = fmaxf(mx, fmaxf(fabsf(a), fabsf(b)));
        float xm = __shfl_up(b, 1, 64);
        if (lane == 0) xm = 0.f;    // zero pad col -1
        #pragma unroll
        for (int rr = 0; rr < 4; ++rr) {
            const int k = r - 2 * rr;
            if (k >= 0 && k <= 2)
                A[rr] += wk[3 * k] * xm + wk[3 * k + 1] * a + wk[3 * k + 2] * b;
        }
        lx0[r] = hw_log2(fmaxf(a, 0.f));    // log2(0) = -inf -> exp2 = 0
        lx1[r] = hw_log2(fmaxf(b, 0.f));
        float sl = __shfl_up(lx1[r], 1, 64);
        lxm[r] = (lane == 0) ? NEG_INF : sl;   // pre-barrier (m-independent)
    }

    // ---- Plane max reduce (the only cross-wave dependency) ----
    #pragma unroll
    for (int off = 32; off; off >>= 1)
        mx = fmaxf(mx, __shfl_down(mx, off, 64));
    if (lane == 0) smax[wid] = mx;
    __syncthreads();
    float mm = smax[0];
    #pragma unroll
    for (int k = 1; k < 16; ++k) mm = fmaxf(mm, smax[k]);
    const float inv_m = hw_rcp(mm + 1.0f);

    float* outres = out + (size_t)bc * 4096;
    float* outp   = out + N_OUT + (size_t)bc * 4096;

    // ---- p-dependent tail: 9 exp2 + finals per output ----
    #pragma unroll
    for (int rr = 0; rr < 4; ++rr) {
        float v = A[rr] * inv_m;                // conv(x/m)
        v = v > 0.f ? v : slope * v;            // PReLU
        float p = v * ww2 + bb2;                // 1x1 dw conv + bias
        p = fminf(fmaxf(p, 1.0f), 110.0f);      // hardtanh

        float s0 = 0.f, s1 = 0.f;               // 2-acc ILP on trans pipe
        #pragma unroll
        for (int k = 0; k < 3; ++k) {
            const int r = 2 * rr + k;
            s0 += hw_exp2(p * lxm[r]);
            s1 += hw_exp2(p * lx0[r]);
            s0 += hw_exp2(p * lx1[r]);
        }
        float mp  = (s0 + s1) * (1.0f / 9.0f) + 1e-12f;
        float res = hw_exp2(hw_log2(mp) * hw_rcp(p));

        const int ho = ho0 + rr;
        __builtin_nontemporal_store(res, &outres[ho * 64 + lane]);
        __builtin_nontemporal_store(p,   &outp  [ho * 64 + lane]);
    }
}

extern "C" void kernel_launch(void* const* d_in, const int* in_sizes, int n_in,
                              void* d_out, int out_size, void* d_ws, size_t ws_size,
                              hipStream_t stream) {
    const float* bottom = (const float*)d_in[0];
    const float* w1     = (const float*)d_in[1];
    const float* a1     = (const float*)d_in[2];
    const float* w2     = (const float*)d_in[3];
    const float* b2     = (const float*)d_in[4];
    float* out = (float*)d_out;

    fused_ppool_v11<<<2048, 1024, 0, stream>>>(bottom, w1, a1, w2, b2, out);
}